// Round 5
// baseline (151.037 us; speedup 1.0000x reference)
//
#include <hip/hip_runtime.h>
#include <math.h>

namespace {

constexpr int kRowF4 = 64 * 256;  // float4 elements per image row (W=64, C=1024)

typedef float vf4 __attribute__((ext_vector_type(4)));

__device__ __forceinline__ int rfl(int x) { return __builtin_amdgcn_readfirstlane(x); }
__device__ __forceinline__ float rflf(float x) {
  union { float f; int i; } u;
  u.f = x;
  u.i = __builtin_amdgcn_readfirstlane(u.i);
  return u.f;
}

__device__ __forceinline__ vf4 splat4(float x) {
  vf4 v = {x, x, x, x};
  return v;
}

// One block per (roi n, pool-row py): computes 7 px x 1024 channels.
// Geometry is block-uniform -> scalarized via readfirstlane; gathers are
// SGPR-base + shared voffset; duplicate corner rows/cols deduped with
// uniform branches. All 7 stores are DEFERRED to kernel end so that no
// per-px vmcnt wait ever covers an outstanding HBM store-ack (stores count
// in vmcnt on CDNA; the per-iteration conservative drain was serializing
// each wave on ~800cy store round-trips).
__global__ __launch_bounds__(256) void roi_pool_kernel(
    const float* __restrict__ img,    // [50, 64, 1024] f32
    const float* __restrict__ rois,   // [N, 4] f32
    const int* __restrict__ stride_p, // scalar 16
    float* __restrict__ out) {        // [N, 7, 7, 1024]
  const int bid = blockIdx.x;
  // XCD-chunked swizzle (bijective when gridDim % 8 == 0)
  const int chunk = gridDim.x >> 3;
  const int swz = ((gridDim.x & 7) == 0) ? ((bid & 7) * chunk + (bid >> 3)) : bid;
  const int n  = swz / 7;
  const int py = swz - n * 7;
  const int c4 = threadIdx.x;  // float4 channel index 0..255

  const float s = (float)(*stride_p);
  // boxes = (rois / stride) / [H, W, H, W] -- mirror reference op order
  const float by1 = rois[n * 4 + 0] / s / 50.0f;
  const float bx1 = rois[n * 4 + 1] / s / 64.0f;
  const float by2 = rois[n * 4 + 2] / s / 50.0f;
  const float bx2 = rois[n * 4 + 3] / s / 64.0f;
  const float stepy = (by2 - by1) * 49.0f / 13.0f;
  const float stepx = (bx2 - bx1) * 63.0f / 13.0f;

  // ---- row geometry for the two sample-rows of this pooled row ----
  const float ys0 = by1 * 49.0f + (float)(2 * py + 0) * stepy;
  const float ys1 = by1 * 49.0f + (float)(2 * py + 1) * stepy;
  const float vy0 = (ys0 >= 0.0f && ys0 <= 49.0f) ? 1.0f : 0.0f;
  const float vy1 = (ys1 >= 0.0f && ys1 <= 49.0f) ? 1.0f : 0.0f;
  const float yf0 = floorf(ys0), yf1 = floorf(ys1);
  const float wy0 = ys0 - yf0, wy1 = ys1 - yf1;
  const int r0i = min(max((int)yf0, 0), 49);
  const int r2i = min(max((int)yf1, 0), 49);
  const int r0 = rfl(r0i);
  const int r1 = rfl(min(r0i + 1, 49));
  const int r2 = rfl(r2i);
  const int r3 = rfl(min(r2i + 1, 49));
  // validity folded into the y-weights (invalid sample -> exact 0, then max)
  const vf4 gy0 = splat4(rflf((1.0f - wy0) * vy0));
  const vf4 fy0 = splat4(rflf(wy0 * vy0));
  const vf4 gy1 = splat4(rflf((1.0f - wy1) * vy1));
  const vf4 fy1 = splat4(rflf(wy1 * vy1));

  const vf4* __restrict__ img4 = (const vf4*)img;
  vf4* __restrict__ out4 = (vf4*)out + (size_t)(n * 49 + py * 7) * 256 + c4;

  const float xb = bx1 * 63.0f;

  vf4 res[7];  // constant-indexed after full unroll -> stays in VGPRs

#pragma unroll
  for (int px = 0; px < 7; ++px) {
    const float xs0 = xb + (float)(2 * px + 0) * stepx;
    const float xs1 = xb + (float)(2 * px + 1) * stepx;
    const float vx0 = (xs0 >= 0.0f && xs0 <= 63.0f) ? 1.0f : 0.0f;
    const float vx1 = (xs1 >= 0.0f && xs1 <= 63.0f) ? 1.0f : 0.0f;
    const float xf0 = floorf(xs0), xf1 = floorf(xs1);
    const float wx0 = xs0 - xf0, wx1 = xs1 - xf1;
    const int c0i = min(max((int)xf0, 0), 63);
    const int c2i = min(max((int)xf1, 0), 63);
    const int c0 = rfl(c0i);
    const int c1 = rfl(min(c0i + 1, 63));
    const int c2 = rfl(c2i);
    const int c3 = rfl(min(c2i + 1, 63));
    const vf4 gx0 = splat4(rflf((1.0f - wx0) * vx0));
    const vf4 fx0 = splat4(rflf(wx0 * vx0));
    const vf4 gx1 = splat4(rflf((1.0f - wx1) * vx1));
    const vf4 fx1 = splat4(rflf(wx1 * vx1));

    // uniform dedup conditions
    const bool c2e0 = (c2 == c0), c2e1 = (c2 == c1);
    const bool c3e1 = (c3 == c1), c3e2 = (c3 == c2);
    const int co0 = c0 * 256, co1 = c1 * 256, co2 = c2 * 256, co3 = c3 * 256;

    // Load row r's needed corners (deduped) and x-blend into the two
    // per-sample values.
    auto rowblend = [&](int r, vf4& b0, vf4& b1) {
      const vf4* rp = img4 + r * kRowF4;  // uniform base
      const vf4 q0 = rp[co0 + c4];
      const vf4 q1 = rp[co1 + c4];
      vf4 q2, q3;
      if (c2e0)      q2 = q0;
      else if (c2e1) q2 = q1;
      else           q2 = rp[co2 + c4];
      if (c3e1)      q3 = q1;
      else if (c3e2) q3 = q2;
      else           q3 = rp[co3 + c4];
      b0 = q0 * gx0 + q1 * fx0;
      b1 = q2 * gx1 + q3 * fx1;
    };

    vf4 b00, b01, b10, b11, b20, b21, b30, b31;
    rowblend(r0, b00, b01);
    if (r1 == r0) { b10 = b00; b11 = b01; }
    else rowblend(r1, b10, b11);
    if (r2 == r0)      { b20 = b00; b21 = b01; }
    else if (r2 == r1) { b20 = b10; b21 = b11; }
    else rowblend(r2, b20, b21);
    if (r3 == r1)      { b30 = b10; b31 = b11; }
    else if (r3 == r2) { b30 = b20; b31 = b21; }
    else rowblend(r3, b30, b31);

    // y-blend the 4 samples of the 2x2 max-pool window and reduce
    vf4 m = b00 * gy0 + b10 * fy0;
    vf4 v = b01 * gy0 + b11 * fy0;
    m = __builtin_elementwise_max(m, v);
    v = b20 * gy1 + b30 * fy1;
    m = __builtin_elementwise_max(m, v);
    v = b21 * gy1 + b31 * fy1;
    m = __builtin_elementwise_max(m, v);

    res[px] = m;
  }

  // All stores at the end: no vmcnt inside the px loop ever waits on a
  // store-ack. Nontemporal: keep the 196 MB output stream out of L2.
#pragma unroll
  for (int px = 0; px < 7; ++px) {
    __builtin_nontemporal_store(res[px], out4 + px * 256);
  }
}

}  // namespace

extern "C" void kernel_launch(void* const* d_in, const int* in_sizes, int n_in,
                              void* d_out, int out_size, void* d_ws, size_t ws_size,
                              hipStream_t stream) {
  const float* img      = (const float*)d_in[0];
  const float* rois     = (const float*)d_in[1];
  const int*   stride_p = (const int*)d_in[2];
  float*       out      = (float*)d_out;

  const int N = in_sizes[1] / 4;      // 1000
  const int nblocks = N * 7;          // one block per (roi, pool-row)
  roi_pool_kernel<<<nblocks, 256, 0, stream>>>(img, rois, stride_p, out);
}

// Round 6
// 107.287 us; speedup vs baseline: 1.4078x; 1.4078x over previous
//
#include <hip/hip_runtime.h>
#include <math.h>

namespace {

constexpr int kRowF4 = 64 * 256;  // float4 elements per image row (W=64, C=1024)

typedef float vf4 __attribute__((ext_vector_type(4)));

__device__ __forceinline__ int rfl(int x) { return __builtin_amdgcn_readfirstlane(x); }
__device__ __forceinline__ float rflf(float x) {
  union { float f; int i; } u;
  u.f = x;
  u.i = __builtin_amdgcn_readfirstlane(u.i);
  return u.f;
}

__device__ __forceinline__ vf4 splat4(float x) {
  vf4 v = {x, x, x, x};
  return v;
}

// One block per OUTPUT POSITION (n, py, px): 256 threads x float4 = 1024 ch.
// Rationale (R5 post-mortem): per-wave px loops serialize on one vmcnt drain
// per px and can't be hidden at <6 waves/SIMD; holding results for deferred
// stores costs 120 VGPR and kills occupancy. Single-position waves have ONE
// drain, ~24 VGPR, and 196k waves of pure TLP. Corner dedup (uniform
// branches), packed <4 x float> blends, folded-validity weights, NT store,
// XCD-chunked swizzle retained.
__global__ __launch_bounds__(256) void roi_pool_kernel(
    const float* __restrict__ img,    // [50, 64, 1024] f32
    const float* __restrict__ rois,   // [N, 4] f32
    const int* __restrict__ stride_p, // scalar 16
    float* __restrict__ out) {        // [N, 7, 7, 1024]
  const int bid = blockIdx.x;
  // XCD-chunked swizzle (bijective when gridDim % 8 == 0): consecutive
  // positions (same roi) land on one XCD's L2.
  const int chunk = gridDim.x >> 3;
  const int pos = ((gridDim.x & 7) == 0) ? ((bid & 7) * chunk + (bid >> 3)) : bid;
  const int n  = pos / 49;
  const int rr = pos - n * 49;
  const int py = rr / 7;
  const int px = rr - py * 7;
  const int c4 = threadIdx.x;  // float4 channel index 0..255

  const float s = (float)(*stride_p);
  // boxes = (rois / stride) / [H, W, H, W] -- mirror reference op order
  const float by1 = rois[n * 4 + 0] / s / 50.0f;
  const float bx1 = rois[n * 4 + 1] / s / 64.0f;
  const float by2 = rois[n * 4 + 2] / s / 50.0f;
  const float bx2 = rois[n * 4 + 3] / s / 64.0f;
  const float stepy = (by2 - by1) * 49.0f / 13.0f;
  const float stepx = (bx2 - bx1) * 63.0f / 13.0f;

  // ---- geometry: two sample rows, two sample cols for this 2x2 window ----
  const float ys0 = by1 * 49.0f + (float)(2 * py + 0) * stepy;
  const float ys1 = by1 * 49.0f + (float)(2 * py + 1) * stepy;
  const float xs0 = bx1 * 63.0f + (float)(2 * px + 0) * stepx;
  const float xs1 = bx1 * 63.0f + (float)(2 * px + 1) * stepx;

  const float vy0 = (ys0 >= 0.0f && ys0 <= 49.0f) ? 1.0f : 0.0f;
  const float vy1 = (ys1 >= 0.0f && ys1 <= 49.0f) ? 1.0f : 0.0f;
  const float vx0 = (xs0 >= 0.0f && xs0 <= 63.0f) ? 1.0f : 0.0f;
  const float vx1 = (xs1 >= 0.0f && xs1 <= 63.0f) ? 1.0f : 0.0f;

  const float yf0 = floorf(ys0), yf1 = floorf(ys1);
  const float xf0 = floorf(xs0), xf1 = floorf(xs1);
  const float wy0 = ys0 - yf0, wy1 = ys1 - yf1;
  const float wx0 = xs0 - xf0, wx1 = xs1 - xf1;

  const int r0i = min(max((int)yf0, 0), 49);
  const int r2i = min(max((int)yf1, 0), 49);
  const int c0i = min(max((int)xf0, 0), 63);
  const int c2i = min(max((int)xf1, 0), 63);
  const int r0 = rfl(r0i);
  const int r1 = rfl(min(r0i + 1, 49));
  const int r2 = rfl(r2i);
  const int r3 = rfl(min(r2i + 1, 49));
  const int c0 = rfl(c0i);
  const int c1 = rfl(min(c0i + 1, 63));
  const int c2 = rfl(c2i);
  const int c3 = rfl(min(c2i + 1, 63));

  // validity folded into weights (invalid sample -> exact 0; max keeps it)
  const vf4 gy0 = splat4(rflf((1.0f - wy0) * vy0));
  const vf4 fy0 = splat4(rflf(wy0 * vy0));
  const vf4 gy1 = splat4(rflf((1.0f - wy1) * vy1));
  const vf4 fy1 = splat4(rflf(wy1 * vy1));
  const vf4 gx0 = splat4(rflf((1.0f - wx0) * vx0));
  const vf4 fx0 = splat4(rflf(wx0 * vx0));
  const vf4 gx1 = splat4(rflf((1.0f - wx1) * vx1));
  const vf4 fx1 = splat4(rflf(wx1 * vx1));

  const vf4* __restrict__ img4 = (const vf4*)img;

  // uniform dedup conditions (c0<=c1<= c2<=c3 orderings hold by construction)
  const bool c2e0 = (c2 == c0), c2e1 = (c2 == c1);
  const bool c3e1 = (c3 == c1), c3e2 = (c3 == c2);
  const int co0 = c0 * 256, co1 = c1 * 256, co2 = c2 * 256, co3 = c3 * 256;

  // Load row r's needed corners (deduped) and x-blend into two samples.
  auto rowblend = [&](int r, vf4& b0, vf4& b1) {
    const vf4* rp = img4 + r * kRowF4;  // uniform base
    const vf4 q0 = rp[co0 + c4];
    const vf4 q1 = rp[co1 + c4];
    vf4 q2, q3;
    if (c2e0)      q2 = q0;
    else if (c2e1) q2 = q1;
    else           q2 = rp[co2 + c4];
    if (c3e1)      q3 = q1;
    else if (c3e2) q3 = q2;
    else           q3 = rp[co3 + c4];
    b0 = q0 * gx0 + q1 * fx0;
    b1 = q2 * gx1 + q3 * fx1;
  };

  vf4 b00, b01, b10, b11, b20, b21, b30, b31;
  rowblend(r0, b00, b01);
  if (r1 == r0) { b10 = b00; b11 = b01; }
  else rowblend(r1, b10, b11);
  if (r2 == r0)      { b20 = b00; b21 = b01; }
  else if (r2 == r1) { b20 = b10; b21 = b11; }
  else rowblend(r2, b20, b21);
  if (r3 == r1)      { b30 = b10; b31 = b11; }
  else if (r3 == r2) { b30 = b20; b31 = b21; }
  else rowblend(r3, b30, b31);

  // y-blend the 4 samples of the 2x2 max-pool window and reduce
  vf4 m = b00 * gy0 + b10 * fy0;
  vf4 v = b01 * gy0 + b11 * fy0;
  m = __builtin_elementwise_max(m, v);
  v = b20 * gy1 + b30 * fy1;
  m = __builtin_elementwise_max(m, v);
  v = b21 * gy1 + b31 * fy1;
  m = __builtin_elementwise_max(m, v);

  // single NT store; wave exits, no store-ack wait before endpgm
  __builtin_nontemporal_store(m, (vf4*)out + (size_t)pos * 256 + c4);
}

}  // namespace

extern "C" void kernel_launch(void* const* d_in, const int* in_sizes, int n_in,
                              void* d_out, int out_size, void* d_ws, size_t ws_size,
                              hipStream_t stream) {
  const float* img      = (const float*)d_in[0];
  const float* rois     = (const float*)d_in[1];
  const int*   stride_p = (const int*)d_in[2];
  float*       out      = (float*)d_out;

  const int N = in_sizes[1] / 4;      // 1000
  const int nblocks = N * 49;         // one block per output position
  roi_pool_kernel<<<nblocks, 256, 0, stream>>>(img, rois, stride_p, out);
}

// Round 7
// 98.804 us; speedup vs baseline: 1.5287x; 1.0859x over previous
//
#include <hip/hip_runtime.h>
#include <math.h>

namespace {

typedef float vf4 __attribute__((ext_vector_type(4)));

constexpr int kRowBytes = 64 * 1024 * 4;  // 262144: one image row (W*C*4)
constexpr int kColBytes = 1024 * 4;       // 4096: one pixel (C*4)

__device__ __forceinline__ int rfl(int x) { return __builtin_amdgcn_readfirstlane(x); }

__device__ __forceinline__ vf4 splat4(float x) {
  vf4 v = {x, x, x, x};
  return v;
}

// ---------------------------------------------------------------------------
// Setup: one thread per (roi, k) computes the y-geometry for py=k and the
// x-geometry for px=k. All divisions / floorf / clamps / validity-folding
// happen HERE, once, instead of in every wave of the 49k-block main kernel.
// Table layout in d_ws (int4/float4 pairs, 32 B per entry):
//   y entry t=(n*7+py): tab[2t]   = {r0B, r1B, r2B, r3B} (row byte offsets)
//                       tab[2t+1] = {gy0, fy0, gy1, fy1} (validity-folded)
//   x entry t=(n*7+px): tab[N*14 + 2t], tab[N*14 + 2t+1] (col byte offsets)
// ---------------------------------------------------------------------------
__global__ void roi_setup_kernel(const float* __restrict__ rois,
                                 const int* __restrict__ stride_p,
                                 int4* __restrict__ tab, int N) {
  const int t = blockIdx.x * 64 + threadIdx.x;
  if (t >= N * 7) return;
  const int n = t / 7;
  const int k = t - n * 7;

  const float s = (float)(*stride_p);
  // boxes = (rois / stride) / [H, W, H, W] -- mirror reference op order
  const float by1 = rois[n * 4 + 0] / s / 50.0f;
  const float bx1 = rois[n * 4 + 1] / s / 64.0f;
  const float by2 = rois[n * 4 + 2] / s / 50.0f;
  const float bx2 = rois[n * 4 + 3] / s / 64.0f;
  const float stepy = (by2 - by1) * 49.0f / 13.0f;
  const float stepx = (bx2 - bx1) * 63.0f / 13.0f;

  // ---- y geometry for py = k ----
  const float ys0 = by1 * 49.0f + (float)(2 * k + 0) * stepy;
  const float ys1 = by1 * 49.0f + (float)(2 * k + 1) * stepy;
  const float vy0 = (ys0 >= 0.0f && ys0 <= 49.0f) ? 1.0f : 0.0f;
  const float vy1 = (ys1 >= 0.0f && ys1 <= 49.0f) ? 1.0f : 0.0f;
  const float yf0 = floorf(ys0), yf1 = floorf(ys1);
  const float wy0 = ys0 - yf0, wy1 = ys1 - yf1;
  const int r0 = min(max((int)yf0, 0), 49);
  const int r1 = min(r0 + 1, 49);
  const int r2 = min(max((int)yf1, 0), 49);
  const int r3 = min(r2 + 1, 49);
  tab[2 * t] = make_int4(r0 * kRowBytes, r1 * kRowBytes,
                         r2 * kRowBytes, r3 * kRowBytes);
  ((float4*)tab)[2 * t + 1] =
      make_float4((1.0f - wy0) * vy0, wy0 * vy0, (1.0f - wy1) * vy1, wy1 * vy1);

  // ---- x geometry for px = k ----
  const float xs0 = bx1 * 63.0f + (float)(2 * k + 0) * stepx;
  const float xs1 = bx1 * 63.0f + (float)(2 * k + 1) * stepx;
  const float vx0 = (xs0 >= 0.0f && xs0 <= 63.0f) ? 1.0f : 0.0f;
  const float vx1 = (xs1 >= 0.0f && xs1 <= 63.0f) ? 1.0f : 0.0f;
  const float xf0 = floorf(xs0), xf1 = floorf(xs1);
  const float wx0 = xs0 - xf0, wx1 = xs1 - xf1;
  const int c0 = min(max((int)xf0, 0), 63);
  const int c1 = min(c0 + 1, 63);
  const int c2 = min(max((int)xf1, 0), 63);
  const int c3 = min(c2 + 1, 63);
  const int xoff = N * 14;
  tab[xoff + 2 * t] = make_int4(c0 * kColBytes, c1 * kColBytes,
                                c2 * kColBytes, c3 * kColBytes);
  ((float4*)tab)[xoff + 2 * t + 1] =
      make_float4((1.0f - wx0) * vx0, wx0 * vx0, (1.0f - wx1) * vx1, wx1 * vx1);
}

// ---------------------------------------------------------------------------
// Main: one block per output position. Per wave: 2 uniform table loads,
// 8 readfirstlanes, ~10 deduped gathers (uniform base + shared c4*16
// voffset -> zero per-load VALU), ~35 packed blends, 1 NT store.
// ---------------------------------------------------------------------------
__global__ __launch_bounds__(256) void roi_pool_tab(
    const float* __restrict__ img,
    const int4* __restrict__ tab, int N,
    float* __restrict__ out) {
  const int bid = blockIdx.x;
  // XCD-chunked swizzle (bijective when gridDim % 8 == 0)
  const int chunk = gridDim.x >> 3;
  const int pos = ((gridDim.x & 7) == 0) ? ((bid & 7) * chunk + (bid >> 3)) : bid;
  const int n  = pos / 49;
  const int rr = pos - n * 49;
  const int py = rr / 7;
  const int px = rr - py * 7;
  const int c4 = threadIdx.x;

  const int yt = 2 * (n * 7 + py);
  const int xt = N * 14 + 2 * (n * 7 + px);
  const int4   yi = tab[yt];
  const float4 yw = ((const float4*)tab)[yt + 1];
  const int4   xi = tab[xt];
  const float4 xw = ((const float4*)tab)[xt + 1];

  // force offsets into SGPRs (guarantees scalar base folding for the gathers)
  const int r0 = rfl(yi.x), r1 = rfl(yi.y), r2 = rfl(yi.z), r3 = rfl(yi.w);
  const int c0 = rfl(xi.x), c1 = rfl(xi.y), c2 = rfl(xi.z), c3 = rfl(xi.w);

  const vf4 gy0 = splat4(yw.x), fy0 = splat4(yw.y);
  const vf4 gy1 = splat4(yw.z), fy1 = splat4(yw.w);
  const vf4 gx0 = splat4(xw.x), fx0 = splat4(xw.y);
  const vf4 gx1 = splat4(xw.z), fx1 = splat4(xw.w);

  const char* __restrict__ imgb = (const char*)img;
  const int coff = c4 * 16;  // shared per-lane voffset

  // uniform dedup conditions (exact byte-offset equality)
  const bool c2e0 = (c2 == c0), c2e1 = (c2 == c1);
  const bool c3e1 = (c3 == c1), c3e2 = (c3 == c2);

  auto rowblend = [&](int rB, vf4& b0, vf4& b1) {
    const vf4 q0 = *(const vf4*)(imgb + (rB + c0) + coff);
    const vf4 q1 = *(const vf4*)(imgb + (rB + c1) + coff);
    vf4 q2, q3;
    if (c2e0)      q2 = q0;
    else if (c2e1) q2 = q1;
    else           q2 = *(const vf4*)(imgb + (rB + c2) + coff);
    if (c3e1)      q3 = q1;
    else if (c3e2) q3 = q2;
    else           q3 = *(const vf4*)(imgb + (rB + c3) + coff);
    b0 = q0 * gx0 + q1 * fx0;
    b1 = q2 * gx1 + q3 * fx1;
  };

  vf4 b00, b01, b10, b11, b20, b21, b30, b31;
  rowblend(r0, b00, b01);
  if (r1 == r0) { b10 = b00; b11 = b01; }
  else rowblend(r1, b10, b11);
  if (r2 == r0)      { b20 = b00; b21 = b01; }
  else if (r2 == r1) { b20 = b10; b21 = b11; }
  else rowblend(r2, b20, b21);
  if (r3 == r1)      { b30 = b10; b31 = b11; }
  else if (r3 == r2) { b30 = b20; b31 = b21; }
  else rowblend(r3, b30, b31);

  vf4 m = b00 * gy0 + b10 * fy0;
  vf4 v = b01 * gy0 + b11 * fy0;
  m = __builtin_elementwise_max(m, v);
  v = b20 * gy1 + b30 * fy1;
  m = __builtin_elementwise_max(m, v);
  v = b21 * gy1 + b31 * fy1;
  m = __builtin_elementwise_max(m, v);

  __builtin_nontemporal_store(m, (vf4*)out + (size_t)pos * 256 + c4);
}

// ---------------------------------------------------------------------------
// Fallback (R6 kernel): self-contained, used only if ws_size is too small.
// ---------------------------------------------------------------------------
__device__ __forceinline__ float rflf(float x) {
  union { float f; int i; } u;
  u.f = x;
  u.i = __builtin_amdgcn_readfirstlane(u.i);
  return u.f;
}

__global__ __launch_bounds__(256) void roi_pool_kernel(
    const float* __restrict__ img, const float* __restrict__ rois,
    const int* __restrict__ stride_p, float* __restrict__ out) {
  const int bid = blockIdx.x;
  const int chunk = gridDim.x >> 3;
  const int pos = ((gridDim.x & 7) == 0) ? ((bid & 7) * chunk + (bid >> 3)) : bid;
  const int n  = pos / 49;
  const int rr = pos - n * 49;
  const int py = rr / 7;
  const int px = rr - py * 7;
  const int c4 = threadIdx.x;

  const float s = (float)(*stride_p);
  const float by1 = rois[n * 4 + 0] / s / 50.0f;
  const float bx1 = rois[n * 4 + 1] / s / 64.0f;
  const float by2 = rois[n * 4 + 2] / s / 50.0f;
  const float bx2 = rois[n * 4 + 3] / s / 64.0f;
  const float stepy = (by2 - by1) * 49.0f / 13.0f;
  const float stepx = (bx2 - bx1) * 63.0f / 13.0f;

  const float ys0 = by1 * 49.0f + (float)(2 * py + 0) * stepy;
  const float ys1 = by1 * 49.0f + (float)(2 * py + 1) * stepy;
  const float xs0 = bx1 * 63.0f + (float)(2 * px + 0) * stepx;
  const float xs1 = bx1 * 63.0f + (float)(2 * px + 1) * stepx;
  const float vy0 = (ys0 >= 0.0f && ys0 <= 49.0f) ? 1.0f : 0.0f;
  const float vy1 = (ys1 >= 0.0f && ys1 <= 49.0f) ? 1.0f : 0.0f;
  const float vx0 = (xs0 >= 0.0f && xs0 <= 63.0f) ? 1.0f : 0.0f;
  const float vx1 = (xs1 >= 0.0f && xs1 <= 63.0f) ? 1.0f : 0.0f;
  const float yf0 = floorf(ys0), yf1 = floorf(ys1);
  const float xf0 = floorf(xs0), xf1 = floorf(xs1);
  const float wy0 = ys0 - yf0, wy1 = ys1 - yf1;
  const float wx0 = xs0 - xf0, wx1 = xs1 - xf1;
  const int r0i = min(max((int)yf0, 0), 49);
  const int r2i = min(max((int)yf1, 0), 49);
  const int c0i = min(max((int)xf0, 0), 63);
  const int c2i = min(max((int)xf1, 0), 63);
  const int r0 = rfl(r0i), r1 = rfl(min(r0i + 1, 49));
  const int r2 = rfl(r2i), r3 = rfl(min(r2i + 1, 49));
  const int c0 = rfl(c0i), c1 = rfl(min(c0i + 1, 63));
  const int c2 = rfl(c2i), c3 = rfl(min(c2i + 1, 63));
  const vf4 gy0 = splat4(rflf((1.0f - wy0) * vy0));
  const vf4 fy0 = splat4(rflf(wy0 * vy0));
  const vf4 gy1 = splat4(rflf((1.0f - wy1) * vy1));
  const vf4 fy1 = splat4(rflf(wy1 * vy1));
  const vf4 gx0 = splat4(rflf((1.0f - wx0) * vx0));
  const vf4 fx0 = splat4(rflf(wx0 * vx0));
  const vf4 gx1 = splat4(rflf((1.0f - wx1) * vx1));
  const vf4 fx1 = splat4(rflf(wx1 * vx1));

  const vf4* __restrict__ img4 = (const vf4*)img;
  const bool c2e0 = (c2 == c0), c2e1 = (c2 == c1);
  const bool c3e1 = (c3 == c1), c3e2 = (c3 == c2);
  const int co0 = c0 * 256, co1 = c1 * 256, co2 = c2 * 256, co3 = c3 * 256;

  auto rowblend = [&](int r, vf4& b0, vf4& b1) {
    const vf4* rp = img4 + r * (64 * 256);
    const vf4 q0 = rp[co0 + c4];
    const vf4 q1 = rp[co1 + c4];
    vf4 q2, q3;
    if (c2e0)      q2 = q0;
    else if (c2e1) q2 = q1;
    else           q2 = rp[co2 + c4];
    if (c3e1)      q3 = q1;
    else if (c3e2) q3 = q2;
    else           q3 = rp[co3 + c4];
    b0 = q0 * gx0 + q1 * fx0;
    b1 = q2 * gx1 + q3 * fx1;
  };

  vf4 b00, b01, b10, b11, b20, b21, b30, b31;
  rowblend(r0, b00, b01);
  if (r1 == r0) { b10 = b00; b11 = b01; }
  else rowblend(r1, b10, b11);
  if (r2 == r0)      { b20 = b00; b21 = b01; }
  else if (r2 == r1) { b20 = b10; b21 = b11; }
  else rowblend(r2, b20, b21);
  if (r3 == r1)      { b30 = b10; b31 = b11; }
  else if (r3 == r2) { b30 = b20; b31 = b21; }
  else rowblend(r3, b30, b31);

  vf4 m = b00 * gy0 + b10 * fy0;
  vf4 v = b01 * gy0 + b11 * fy0;
  m = __builtin_elementwise_max(m, v);
  v = b20 * gy1 + b30 * fy1;
  m = __builtin_elementwise_max(m, v);
  v = b21 * gy1 + b31 * fy1;
  m = __builtin_elementwise_max(m, v);

  __builtin_nontemporal_store(m, (vf4*)out + (size_t)pos * 256 + c4);
}

}  // namespace

extern "C" void kernel_launch(void* const* d_in, const int* in_sizes, int n_in,
                              void* d_out, int out_size, void* d_ws, size_t ws_size,
                              hipStream_t stream) {
  const float* img      = (const float*)d_in[0];
  const float* rois     = (const float*)d_in[1];
  const int*   stride_p = (const int*)d_in[2];
  float*       out      = (float*)d_out;

  const int N = in_sizes[1] / 4;              // 1000
  const size_t tab_bytes = (size_t)N * 28 * 16;  // 28 int4s per roi (y+x tables)

  if (ws_size >= tab_bytes) {
    int4* tab = (int4*)d_ws;
    const int nt = N * 7;
    roi_setup_kernel<<<(nt + 63) / 64, 64, 0, stream>>>(rois, stride_p, tab, N);
    roi_pool_tab<<<N * 49, 256, 0, stream>>>(img, tab, N, out);
  } else {
    roi_pool_kernel<<<N * 49, 256, 0, stream>>>(img, rois, stride_p, out);
  }
}

// Round 8
// 86.358 us; speedup vs baseline: 1.7490x; 1.1441x over previous
//
#include <hip/hip_runtime.h>
#include <math.h>

namespace {

typedef float vf4 __attribute__((ext_vector_type(4)));

constexpr int kRowBytes = 64 * 1024 * 4;  // 262144: one image row (W*C*4)
constexpr int kColBytes = 1024 * 4;       // 4096: one pixel (C*4)

__device__ __forceinline__ int rfl(int x) { return __builtin_amdgcn_readfirstlane(x); }

__device__ __forceinline__ vf4 splat4(float x) {
  vf4 v = {x, x, x, x};
  return v;
}

// ---------------------------------------------------------------------------
// Sort: deterministic bitonic sort of the N rois by quantized y-center.
// One block, 512 threads, LDS-resident (1024 padded elements).
// perm[sorted_slot] = original roi index. XCD-chunked dispatch then gives
// each XCD a contiguous y-band whose feature-map rows FIT its 4 MB L2
// (random roi order thrashes it: image is 13 MB > 4 MB).
// ---------------------------------------------------------------------------
__global__ __launch_bounds__(512) void roi_sort_kernel(
    const float* __restrict__ rois, const int* __restrict__ stride_p,
    int* __restrict__ perm, int N) {
  __shared__ unsigned sk[1024];
  const int tid = threadIdx.x;
  const float s = (float)(*stride_p);

  for (int i = tid; i < 1024; i += 512) {
    unsigned key = 0xFFFFFFFFu;
    if (i < N) {
      const float yc = (rois[i * 4 + 0] + rois[i * 4 + 2]) * 0.5f / s;  // rows
      int q = (int)(yc * (1024.0f / 50.0f));
      q = min(max(q, 0), 1023);
      key = ((unsigned)q << 10) | (unsigned)i;  // composite -> deterministic
    }
    sk[i] = key;
  }
  __syncthreads();

  for (unsigned k = 2; k <= 1024; k <<= 1) {
    for (unsigned j = k >> 1; j > 0; j >>= 1) {
      const unsigned t = tid;  // 512 compare pairs
      const unsigned i1 = ((t & ~(j - 1)) << 1) | (t & (j - 1));
      const unsigned i2 = i1 | j;
      const unsigned a = sk[i1], b = sk[i2];
      const bool up = ((i1 & k) == 0);
      if ((a > b) == up) { sk[i1] = b; sk[i2] = a; }
      __syncthreads();
    }
  }

  for (int i = tid; i < N; i += 512) perm[i] = (int)(sk[i] & 1023u);
}

// ---------------------------------------------------------------------------
// Setup: one thread per (sorted_slot, k). Tables are written in SORTED
// order; all divisions/floors/clamps/validity-folding happen here once.
//   y entry t=(sn*7+py): tab[2t] = row byte offsets, tab[2t+1] = y-weights
//   x entry t=(sn*7+px): tab[N*14+2t], tab[N*14+2t+1]   (col offsets/weights)
// ---------------------------------------------------------------------------
__global__ void roi_setup_kernel(const float* __restrict__ rois,
                                 const int* __restrict__ stride_p,
                                 const int* __restrict__ perm,
                                 int4* __restrict__ tab, int N) {
  const int t = blockIdx.x * 64 + threadIdx.x;
  if (t >= N * 7) return;
  const int sn = t / 7;
  const int k = t - sn * 7;
  const int n = perm[sn];

  const float s = (float)(*stride_p);
  // boxes = (rois / stride) / [H, W, H, W] -- mirror reference op order
  const float by1 = rois[n * 4 + 0] / s / 50.0f;
  const float bx1 = rois[n * 4 + 1] / s / 64.0f;
  const float by2 = rois[n * 4 + 2] / s / 50.0f;
  const float bx2 = rois[n * 4 + 3] / s / 64.0f;
  const float stepy = (by2 - by1) * 49.0f / 13.0f;
  const float stepx = (bx2 - bx1) * 63.0f / 13.0f;

  // ---- y geometry for py = k ----
  const float ys0 = by1 * 49.0f + (float)(2 * k + 0) * stepy;
  const float ys1 = by1 * 49.0f + (float)(2 * k + 1) * stepy;
  const float vy0 = (ys0 >= 0.0f && ys0 <= 49.0f) ? 1.0f : 0.0f;
  const float vy1 = (ys1 >= 0.0f && ys1 <= 49.0f) ? 1.0f : 0.0f;
  const float yf0 = floorf(ys0), yf1 = floorf(ys1);
  const float wy0 = ys0 - yf0, wy1 = ys1 - yf1;
  const int r0 = min(max((int)yf0, 0), 49);
  const int r1 = min(r0 + 1, 49);
  const int r2 = min(max((int)yf1, 0), 49);
  const int r3 = min(r2 + 1, 49);
  tab[2 * t] = make_int4(r0 * kRowBytes, r1 * kRowBytes,
                         r2 * kRowBytes, r3 * kRowBytes);
  ((float4*)tab)[2 * t + 1] =
      make_float4((1.0f - wy0) * vy0, wy0 * vy0, (1.0f - wy1) * vy1, wy1 * vy1);

  // ---- x geometry for px = k ----
  const float xs0 = bx1 * 63.0f + (float)(2 * k + 0) * stepx;
  const float xs1 = bx1 * 63.0f + (float)(2 * k + 1) * stepx;
  const float vx0 = (xs0 >= 0.0f && xs0 <= 63.0f) ? 1.0f : 0.0f;
  const float vx1 = (xs1 >= 0.0f && xs1 <= 63.0f) ? 1.0f : 0.0f;
  const float xf0 = floorf(xs0), xf1 = floorf(xs1);
  const float wx0 = xs0 - xf0, wx1 = xs1 - xf1;
  const int c0 = min(max((int)xf0, 0), 63);
  const int c1 = min(c0 + 1, 63);
  const int c2 = min(max((int)xf1, 0), 63);
  const int c3 = min(c2 + 1, 63);
  const int xoff = N * 14;
  tab[xoff + 2 * t] = make_int4(c0 * kColBytes, c1 * kColBytes,
                                c2 * kColBytes, c3 * kColBytes);
  ((float4*)tab)[xoff + 2 * t + 1] =
      make_float4((1.0f - wx0) * vx0, wx0 * vx0, (1.0f - wx1) * vx1, wx1 * vx1);
}

// ---------------------------------------------------------------------------
// Main: one block per SORTED output position. Per wave: perm + 2 uniform
// table loads (independent, issued together), 8 readfirstlanes, ~10 deduped
// gathers (uniform base + shared c4*16 voffset), ~35 packed blends, 1 NT
// store to the ORIGINAL roi's output slice.
// ---------------------------------------------------------------------------
__global__ __launch_bounds__(256) void roi_pool_tab(
    const float* __restrict__ img,
    const int4* __restrict__ tab,
    const int* __restrict__ perm, int N,
    float* __restrict__ out) {
  const int bid = blockIdx.x;
  // XCD-chunked swizzle (bijective when gridDim % 8 == 0): each XCD gets a
  // contiguous run of SORTED positions -> a compact y-band in its L2.
  const int chunk = gridDim.x >> 3;
  const int pos = ((gridDim.x & 7) == 0) ? ((bid & 7) * chunk + (bid >> 3)) : bid;
  const int sn = pos / 49;
  const int rr = pos - sn * 49;
  const int py = rr / 7;
  const int px = rr - py * 7;
  const int c4 = threadIdx.x;

  const int yt = 2 * (sn * 7 + py);
  const int xt = N * 14 + 2 * (sn * 7 + px);
  const int    n  = perm[sn];           // original roi (output addressing)
  const int4   yi = tab[yt];
  const float4 yw = ((const float4*)tab)[yt + 1];
  const int4   xi = tab[xt];
  const float4 xw = ((const float4*)tab)[xt + 1];

  // force offsets into SGPRs (scalar base folding for the gathers)
  const int r0 = rfl(yi.x), r1 = rfl(yi.y), r2 = rfl(yi.z), r3 = rfl(yi.w);
  const int c0 = rfl(xi.x), c1 = rfl(xi.y), c2 = rfl(xi.z), c3 = rfl(xi.w);

  const vf4 gy0 = splat4(yw.x), fy0 = splat4(yw.y);
  const vf4 gy1 = splat4(yw.z), fy1 = splat4(yw.w);
  const vf4 gx0 = splat4(xw.x), fx0 = splat4(xw.y);
  const vf4 gx1 = splat4(xw.z), fx1 = splat4(xw.w);

  const char* __restrict__ imgb = (const char*)img;
  const int coff = c4 * 16;  // shared per-lane voffset

  // uniform dedup conditions (exact byte-offset equality)
  const bool c2e0 = (c2 == c0), c2e1 = (c2 == c1);
  const bool c3e1 = (c3 == c1), c3e2 = (c3 == c2);

  auto rowblend = [&](int rB, vf4& b0, vf4& b1) {
    const vf4 q0 = *(const vf4*)(imgb + (rB + c0) + coff);
    const vf4 q1 = *(const vf4*)(imgb + (rB + c1) + coff);
    vf4 q2, q3;
    if (c2e0)      q2 = q0;
    else if (c2e1) q2 = q1;
    else           q2 = *(const vf4*)(imgb + (rB + c2) + coff);
    if (c3e1)      q3 = q1;
    else if (c3e2) q3 = q2;
    else           q3 = *(const vf4*)(imgb + (rB + c3) + coff);
    b0 = q0 * gx0 + q1 * fx0;
    b1 = q2 * gx1 + q3 * fx1;
  };

  vf4 b00, b01, b10, b11, b20, b21, b30, b31;
  rowblend(r0, b00, b01);
  if (r1 == r0) { b10 = b00; b11 = b01; }
  else rowblend(r1, b10, b11);
  if (r2 == r0)      { b20 = b00; b21 = b01; }
  else if (r2 == r1) { b20 = b10; b21 = b11; }
  else rowblend(r2, b20, b21);
  if (r3 == r1)      { b30 = b10; b31 = b11; }
  else if (r3 == r2) { b30 = b20; b31 = b21; }
  else rowblend(r3, b30, b31);

  vf4 m = b00 * gy0 + b10 * fy0;
  vf4 v = b01 * gy0 + b11 * fy0;
  m = __builtin_elementwise_max(m, v);
  v = b20 * gy1 + b30 * fy1;
  m = __builtin_elementwise_max(m, v);
  v = b21 * gy1 + b31 * fy1;
  m = __builtin_elementwise_max(m, v);

  __builtin_nontemporal_store(m, (vf4*)out + ((size_t)n * 49 + rr) * 256 + c4);
}

// ---------------------------------------------------------------------------
// Fallback (R6 kernel, self-contained): used only if ws_size is too small.
// ---------------------------------------------------------------------------
__device__ __forceinline__ float rflf(float x) {
  union { float f; int i; } u;
  u.f = x;
  u.i = __builtin_amdgcn_readfirstlane(u.i);
  return u.f;
}

__global__ __launch_bounds__(256) void roi_pool_kernel(
    const float* __restrict__ img, const float* __restrict__ rois,
    const int* __restrict__ stride_p, float* __restrict__ out) {
  const int bid = blockIdx.x;
  const int chunk = gridDim.x >> 3;
  const int pos = ((gridDim.x & 7) == 0) ? ((bid & 7) * chunk + (bid >> 3)) : bid;
  const int n  = pos / 49;
  const int rr = pos - n * 49;
  const int py = rr / 7;
  const int px = rr - py * 7;
  const int c4 = threadIdx.x;

  const float s = (float)(*stride_p);
  const float by1 = rois[n * 4 + 0] / s / 50.0f;
  const float bx1 = rois[n * 4 + 1] / s / 64.0f;
  const float by2 = rois[n * 4 + 2] / s / 50.0f;
  const float bx2 = rois[n * 4 + 3] / s / 64.0f;
  const float stepy = (by2 - by1) * 49.0f / 13.0f;
  const float stepx = (bx2 - bx1) * 63.0f / 13.0f;

  const float ys0 = by1 * 49.0f + (float)(2 * py + 0) * stepy;
  const float ys1 = by1 * 49.0f + (float)(2 * py + 1) * stepy;
  const float xs0 = bx1 * 63.0f + (float)(2 * px + 0) * stepx;
  const float xs1 = bx1 * 63.0f + (float)(2 * px + 1) * stepx;
  const float vy0 = (ys0 >= 0.0f && ys0 <= 49.0f) ? 1.0f : 0.0f;
  const float vy1 = (ys1 >= 0.0f && ys1 <= 49.0f) ? 1.0f : 0.0f;
  const float vx0 = (xs0 >= 0.0f && xs0 <= 63.0f) ? 1.0f : 0.0f;
  const float vx1 = (xs1 >= 0.0f && xs1 <= 63.0f) ? 1.0f : 0.0f;
  const float yf0 = floorf(ys0), yf1 = floorf(ys1);
  const float xf0 = floorf(xs0), xf1 = floorf(xs1);
  const float wy0 = ys0 - yf0, wy1 = ys1 - yf1;
  const float wx0 = xs0 - xf0, wx1 = xs1 - xf1;
  const int r0i = min(max((int)yf0, 0), 49);
  const int r2i = min(max((int)yf1, 0), 49);
  const int c0i = min(max((int)xf0, 0), 63);
  const int c2i = min(max((int)xf1, 0), 63);
  const int r0 = rfl(r0i), r1 = rfl(min(r0i + 1, 49));
  const int r2 = rfl(r2i), r3 = rfl(min(r2i + 1, 49));
  const int c0 = rfl(c0i), c1 = rfl(min(c0i + 1, 63));
  const int c2 = rfl(c2i), c3 = rfl(min(c2i + 1, 63));
  const vf4 gy0 = splat4(rflf((1.0f - wy0) * vy0));
  const vf4 fy0 = splat4(rflf(wy0 * vy0));
  const vf4 gy1 = splat4(rflf((1.0f - wy1) * vy1));
  const vf4 fy1 = splat4(rflf(wy1 * vy1));
  const vf4 gx0 = splat4(rflf((1.0f - wx0) * vx0));
  const vf4 fx0 = splat4(rflf(wx0 * vx0));
  const vf4 gx1 = splat4(rflf((1.0f - wx1) * vx1));
  const vf4 fx1 = splat4(rflf(wx1 * vx1));

  const vf4* __restrict__ img4 = (const vf4*)img;
  const bool c2e0 = (c2 == c0), c2e1 = (c2 == c1);
  const bool c3e1 = (c3 == c1), c3e2 = (c3 == c2);
  const int co0 = c0 * 256, co1 = c1 * 256, co2 = c2 * 256, co3 = c3 * 256;

  auto rowblend = [&](int r, vf4& b0, vf4& b1) {
    const vf4* rp = img4 + r * (64 * 256);
    const vf4 q0 = rp[co0 + c4];
    const vf4 q1 = rp[co1 + c4];
    vf4 q2, q3;
    if (c2e0)      q2 = q0;
    else if (c2e1) q2 = q1;
    else           q2 = rp[co2 + c4];
    if (c3e1)      q3 = q1;
    else if (c3e2) q3 = q2;
    else           q3 = rp[co3 + c4];
    b0 = q0 * gx0 + q1 * fx0;
    b1 = q2 * gx1 + q3 * fx1;
  };

  vf4 b00, b01, b10, b11, b20, b21, b30, b31;
  rowblend(r0, b00, b01);
  if (r1 == r0) { b10 = b00; b11 = b01; }
  else rowblend(r1, b10, b11);
  if (r2 == r0)      { b20 = b00; b21 = b01; }
  else if (r2 == r1) { b20 = b10; b21 = b11; }
  else rowblend(r2, b20, b21);
  if (r3 == r1)      { b30 = b10; b31 = b11; }
  else if (r3 == r2) { b30 = b20; b31 = b21; }
  else rowblend(r3, b30, b31);

  vf4 m = b00 * gy0 + b10 * fy0;
  vf4 v = b01 * gy0 + b11 * fy0;
  m = __builtin_elementwise_max(m, v);
  v = b20 * gy1 + b30 * fy1;
  m = __builtin_elementwise_max(m, v);
  v = b21 * gy1 + b31 * fy1;
  m = __builtin_elementwise_max(m, v);

  __builtin_nontemporal_store(m, (vf4*)out + (size_t)pos * 256 + c4);
}

}  // namespace

extern "C" void kernel_launch(void* const* d_in, const int* in_sizes, int n_in,
                              void* d_out, int out_size, void* d_ws, size_t ws_size,
                              hipStream_t stream) {
  const float* img      = (const float*)d_in[0];
  const float* rois     = (const float*)d_in[1];
  const int*   stride_p = (const int*)d_in[2];
  float*       out      = (float*)d_out;

  const int N = in_sizes[1] / 4;                     // 1000
  const size_t tab_bytes  = (size_t)N * 28 * 16;     // 28 int4s per roi
  const size_t perm_bytes = (size_t)((N + 63) & ~63) * sizeof(int);

  if (ws_size >= tab_bytes + perm_bytes && N <= 1024) {
    int4* tab  = (int4*)d_ws;
    int*  perm = (int*)((char*)d_ws + tab_bytes);
    roi_sort_kernel<<<1, 512, 0, stream>>>(rois, stride_p, perm, N);
    roi_setup_kernel<<<(N * 7 + 63) / 64, 64, 0, stream>>>(rois, stride_p, perm,
                                                           tab, N);
    roi_pool_tab<<<N * 49, 256, 0, stream>>>(img, tab, perm, N, out);
  } else {
    roi_pool_kernel<<<N * 49, 256, 0, stream>>>(img, rois, stride_p, out);
  }
}